// Round 9
// baseline (697.703 us; speedup 1.0000x reference)
//
#include <hip/hip_runtime.h>

typedef __bf16 bf16x8 __attribute__((ext_vector_type(8)));
typedef float f32x4 __attribute__((ext_vector_type(4)));
typedef unsigned short u16x8 __attribute__((ext_vector_type(8)));

#define S_LEN 2048
#define NHEAD 16
#define HDIM  64
#define EMB   1024
#define NBLK  768

__device__ __forceinline__ ushort f2b(float v) {
  union { float f; unsigned u; } x; x.f = v;
  unsigned r = (x.u + 0x7fffu + ((x.u >> 16) & 1u)) >> 16;
  return (ushort)r;
}

// pack two floats as truncated bf16 pair (a -> low16, b -> high16)
__device__ __forceinline__ unsigned packtrunc(float a, float b) {
  union { float f; unsigned u; } x, y; x.f = a; y.f = b;
  return (x.u >> 16) | (y.u & 0xFFFF0000u);
}

// async global->LDS, 16B per lane; LDS dest = wave-uniform base + lane*16
typedef const __attribute__((address_space(1))) unsigned int* gp1_t;
typedef __attribute__((address_space(3))) unsigned int* lp3_t;
__device__ __forceinline__ void gld16(const ushort* g, const ushort* l) {
  __builtin_amdgcn_global_load_lds((gp1_t)(unsigned long long)(uintptr_t)g,
                                   (lp3_t)(unsigned int)(uintptr_t)l, 16, 0, 0);
}

// device-scope grid barrier (generation counter; all NBLK blocks co-resident
// by construction: LDS 51200*3=150KB<=160KB, launch_bounds(256,3) caps VGPR).
__device__ __forceinline__ void gridbar(unsigned* bar) {
  __syncthreads();
  if (threadIdx.x == 0) {
    __threadfence();  // release: drain + write back this XCD's dirty L2
    unsigned g = __hip_atomic_load(&bar[1], __ATOMIC_RELAXED, __HIP_MEMORY_SCOPE_AGENT);
    unsigned a = __hip_atomic_fetch_add(&bar[0], 1u, __ATOMIC_ACQ_REL, __HIP_MEMORY_SCOPE_AGENT);
    if (a == NBLK - 1) {
      __hip_atomic_store(&bar[0], 0u, __ATOMIC_RELAXED, __HIP_MEMORY_SCOPE_AGENT);
      __hip_atomic_store(&bar[1], g + 1u, __ATOMIC_RELEASE, __HIP_MEMORY_SCOPE_AGENT);
    } else {
      while (__hip_atomic_load(&bar[1], __ATOMIC_ACQUIRE, __HIP_MEMORY_SCOPE_AGENT) == g)
        __builtin_amdgcn_s_sleep(8);
    }
    __threadfence();  // acquire: invalidate stale L1 / L2 lines
  }
  __syncthreads();
}

union LdsU {
  float wt[32][33];                                      // prep transpose tile
  struct { ushort A[2][4096]; ushort B[2][4096]; } g;    // gemm dbuf (32 KB)
  struct { ushort K[2][4096]; ushort V[2][4096]; ushort P[9216]; } a;  // attn (50 KB)
};

// ---------------- GEMM tile: C[128,128] = A[M,K] x Bt[N,K]^T ----------------
// m97 structure: gld16 dwordx4 staging, unpadded BK=32, dbuf, 1 barrier/iter.
template <int EPI>
__device__ __forceinline__ void gemm_tile(
    int mi, int ni, const ushort* __restrict__ A, const ushort* __restrict__ Bt,
    int K, int N, ushort* __restrict__ outQ, ushort* __restrict__ outK,
    ushort* __restrict__ outVt, float* __restrict__ outF,
    const float* __restrict__ bias, LdsU& lds) {
  const int tid = threadIdx.x;
  const int lane = tid & 63, ln = lane & 15, quad = lane >> 4;
  const int wave = tid >> 6, wm = wave >> 1, wn = wave & 1;
  const long m0 = (long)mi * 128, n0 = (long)ni * 128;

  const int sr = lane >> 2, sc = (lane & 3) * 8;
  const ushort* AgL = A + (m0 + 32 * wave + sr) * (long)K + sc;
  const ushort* BgL = Bt + (n0 + 32 * wave + sr) * (long)K + sc;

  f32x4 acc[4][4] = {};
  const int KT = K >> 5;

  {
    ushort* as = &lds.g.A[0][32 * wave * 32];
    ushort* bs = &lds.g.B[0][32 * wave * 32];
    gld16(AgL, as);
    gld16(AgL + 16 * (long)K, as + 16 * 32);
    gld16(BgL, bs);
    gld16(BgL + 16 * (long)K, bs + 16 * 32);
  }
  __syncthreads();

  for (int kt = 0; kt < KT; ++kt) {
    if (kt + 1 < KT) {
      const int nb = (kt + 1) & 1;
      const ushort* a = AgL + (kt + 1) * 32;
      const ushort* b = BgL + (kt + 1) * 32;
      ushort* as = &lds.g.A[nb][32 * wave * 32];
      ushort* bs = &lds.g.B[nb][32 * wave * 32];
      gld16(a, as);
      gld16(a + 16 * (long)K, as + 16 * 32);
      gld16(b, bs);
      gld16(b + 16 * (long)K, bs + 16 * 32);
    }
    const ushort* Ac = &lds.g.A[kt & 1][0];
    const ushort* Bc = &lds.g.B[kt & 1][0];
    bf16x8 af[4], bf[4];
#pragma unroll
    for (int mt = 0; mt < 4; ++mt)
      af[mt] = *(const bf16x8*)(Ac + (wm * 64 + mt * 16 + ln) * 32 + quad * 8);
#pragma unroll
    for (int nt = 0; nt < 4; ++nt)
      bf[nt] = *(const bf16x8*)(Bc + (wn * 64 + nt * 16 + ln) * 32 + quad * 8);
#pragma unroll
    for (int mt = 0; mt < 4; ++mt)
#pragma unroll
      for (int nt = 0; nt < 4; ++nt)
        acc[mt][nt] = __builtin_amdgcn_mfma_f32_16x16x32_bf16(af[mt], bf[nt], acc[mt][nt], 0, 0, 0);
    __syncthreads();
  }

  if (EPI == 0) {
    const int sel = ni >> 3;  // 0:Q 1:K 2:V (block-uniform)
    if (sel == 2) {
      // V transposed [bh][d][s]; 4 regs = 4 consecutive s -> uint2
#pragma unroll
      for (int mt = 0; mt < 4; ++mt) {
        const long mbase = m0 + wm * 64 + mt * 16 + quad * 4;
        const long bb = mbase >> 11, s = mbase & 2047;
#pragma unroll
        for (int nt = 0; nt < 4; ++nt) {
          const int nn = (int)(((n0 & 1023) + wn * 64 + nt * 16 + ln));
          const int h = nn >> 6, d = nn & 63;
          uint2 val;
          val.x = (unsigned)f2b(acc[mt][nt][0]) | ((unsigned)f2b(acc[mt][nt][1]) << 16);
          val.y = (unsigned)f2b(acc[mt][nt][2]) | ((unsigned)f2b(acc[mt][nt][3]) << 16);
          *(uint2*)(outVt + (((bb * NHEAD + h) * (long)HDIM + d) * S_LEN) + s) = val;
        }
      }
    } else {
      ushort* dst = sel == 0 ? outQ : outK;
#pragma unroll
      for (int mt = 0; mt < 4; ++mt) {
#pragma unroll
        for (int nt = 0; nt < 4; ++nt) {
          const int nn = (int)(((n0 & 1023) + wn * 64 + nt * 16 + ln));
          const int h = nn >> 6, d = nn & 63;
#pragma unroll
          for (int r = 0; r < 4; ++r) {
            const long m = m0 + wm * 64 + mt * 16 + quad * 4 + r;
            const long bb = m >> 11, s = m & 2047;
            dst[(((bb * NHEAD + h) * S_LEN) + s) * HDIM + d] = f2b(acc[mt][nt][r]);
          }
        }
      }
    }
  } else {
#pragma unroll
    for (int mt = 0; mt < 4; ++mt) {
#pragma unroll
      for (int nt = 0; nt < 4; ++nt) {
#pragma unroll
        for (int r = 0; r < 4; ++r) {
          const long m = m0 + wm * 64 + mt * 16 + quad * 4 + r;
          const long n = n0 + wn * 64 + nt * 16 + ln;
          outF[m * (long)N + n] = acc[mt][nt][r] + bias[n];
        }
      }
    }
  }
}

// ---------------- flash attention job (v7 structure) ----------------
// 128 q-rows; 4 waves x 32 rows (two 16-row halves sharing K/V frags).
// S^T = K x Q^T -> lane holds 4 consecutive keys -> one b64 P-write.
// 64-key tiles, gld16 double-buffered -> one barrier per tile.
__device__ __forceinline__ void attn_job(
    int bh, int qb, const ushort* __restrict__ Q, const ushort* __restrict__ Kg,
    const ushort* __restrict__ Vt, ushort* __restrict__ Y, LdsU& lds) {
  const int tid = threadIdx.x;
  const int wave = tid >> 6, lane = tid & 63, ln = lane & 15, quad = lane >> 4;
  const int q0 = qb * 128;
  const size_t base = (size_t)bh * S_LEN * HDIM;
  const int ntiles = 2 * qb + 2;
  const int qbase = q0 + wave * 32;

  const u16x8 ob = {0x3F80, 0x3F80, 0x3F80, 0x3F80, 0x3F80, 0x3F80, 0x3F80, 0x3F80};
  const bf16x8 ones = __builtin_bit_cast(bf16x8, ob);

  bf16x8 qf[2][2];
#pragma unroll
  for (int mt = 0; mt < 2; ++mt)
#pragma unroll
    for (int ks2 = 0; ks2 < 2; ++ks2)
      qf[mt][ks2] = *(const bf16x8*)(Q + base + (size_t)(qbase + mt * 16 + ln) * HDIM +
                                     ks2 * 32 + quad * 8);

  f32x4 acc[2][4] = {};
  f32x4 accl[2] = {};

  const int sr = lane >> 2, sc = (lane & 3) * 8;
  const ushort* KgL = Kg + base + (size_t)(16 * wave + sr) * HDIM + sc;
  const ushort* VgL = Vt + base + (size_t)(16 * wave + sr) * S_LEN + sc;

  {
    ushort* kb = &lds.a.K[0][16 * wave * 32];
    ushort* vb = &lds.a.V[0][16 * wave * 32];
    gld16(KgL, kb);
    gld16(KgL + 32, kb + 2048);
    gld16(VgL, vb);
    gld16(VgL + 32, vb + 2048);
  }
  __syncthreads();

  ushort* Pw0 = lds.a.P + wave * 2304;
  ushort* Pw1 = Pw0 + 1152;

  for (int kt = 0; kt < ntiles; ++kt) {
    const int cur = kt & 1;
    const int k0 = kt * 64;
    if (kt + 1 < ntiles) {
      const int nb = cur ^ 1;
      const size_t k1 = (size_t)(k0 + 64);
      ushort* kb = &lds.a.K[nb][16 * wave * 32];
      ushort* vb = &lds.a.V[nb][16 * wave * 32];
      gld16(KgL + k1 * HDIM, kb);
      gld16(KgL + k1 * HDIM + 32, kb + 2048);
      gld16(VgL + k1, vb);
      gld16(VgL + k1 + 32, vb + 2048);
    }
    const ushort* Kc = &lds.a.K[cur][0];
    const ushort* Vc = &lds.a.V[cur][0];

    if (k0 < qbase + 32) {
      f32x4 sT0[4] = {}, sT1[4] = {};
#pragma unroll
      for (int ks2 = 0; ks2 < 2; ++ks2) {
#pragma unroll
        for (int nt = 0; nt < 4; ++nt) {
          bf16x8 ak = *(const bf16x8*)(Kc + ks2 * 2048 + (nt * 16 + ln) * 32 + quad * 8);
          sT0[nt] = __builtin_amdgcn_mfma_f32_16x16x32_bf16(ak, qf[0][ks2], sT0[nt], 0, 0, 0);
          sT1[nt] = __builtin_amdgcn_mfma_f32_16x16x32_bf16(ak, qf[1][ks2], sT1[nt], 0, 0, 0);
        }
      }

      if (k0 + 63 > qbase) {
        const int thr0 = qbase + ln - k0 - quad * 4;
        const int thr1 = thr0 + 16;
#pragma unroll
        for (int nt = 0; nt < 4; ++nt)
#pragma unroll
          for (int r = 0; r < 4; ++r) {
            if (nt * 16 + r > thr0) sT0[nt][r] = -3.0e38f;
            if (nt * 16 + r > thr1) sT1[nt][r] = -3.0e38f;
          }
      }

      asm volatile("" ::: "memory");
#pragma unroll
      for (int nt = 0; nt < 4; ++nt) {
        uint2 w0, w1;
        w0.x = packtrunc(__builtin_amdgcn_exp2f(sT0[nt][0]), __builtin_amdgcn_exp2f(sT0[nt][1]));
        w0.y = packtrunc(__builtin_amdgcn_exp2f(sT0[nt][2]), __builtin_amdgcn_exp2f(sT0[nt][3]));
        w1.x = packtrunc(__builtin_amdgcn_exp2f(sT1[nt][0]), __builtin_amdgcn_exp2f(sT1[nt][1]));
        w1.y = packtrunc(__builtin_amdgcn_exp2f(sT1[nt][2]), __builtin_amdgcn_exp2f(sT1[nt][3]));
        const int off = ln * 72 + nt * 16 + quad * 4;
        *(uint2*)(Pw0 + off) = w0;
        *(uint2*)(Pw1 + off) = w1;
      }
      asm volatile("" ::: "memory");

#pragma unroll
      for (int ks2 = 0; ks2 < 2; ++ks2) {
        const int rcol = ks2 * 32 + quad * 8;
        bf16x8 ap0 = *(const bf16x8*)(Pw0 + ln * 72 + rcol);
        bf16x8 ap1 = *(const bf16x8*)(Pw1 + ln * 72 + rcol);
        accl[0] = __builtin_amdgcn_mfma_f32_16x16x32_bf16(ap0, ones, accl[0], 0, 0, 0);
        accl[1] = __builtin_amdgcn_mfma_f32_16x16x32_bf16(ap1, ones, accl[1], 0, 0, 0);
#pragma unroll
        for (int t2 = 0; t2 < 4; ++t2) {
          bf16x8 bv = *(const bf16x8*)(Vc + ks2 * 2048 + (t2 * 16 + ln) * 32 + quad * 8);
          acc[0][t2] = __builtin_amdgcn_mfma_f32_16x16x32_bf16(ap0, bv, acc[0][t2], 0, 0, 0);
          acc[1][t2] = __builtin_amdgcn_mfma_f32_16x16x32_bf16(ap1, bv, acc[1][t2], 0, 0, 0);
        }
      }
    }
    __syncthreads();
  }

  const long b = bh >> 4;
  const int h = bh & 15;
#pragma unroll
  for (int mt = 0; mt < 2; ++mt) {
#pragma unroll
    for (int r = 0; r < 4; ++r) {
      float inv = 1.0f / accl[mt][r];
      const int qq = qbase + mt * 16 + quad * 4 + r;
#pragma unroll
      for (int t2 = 0; t2 < 4; ++t2)
        Y[(((b * S_LEN + qq) * NHEAD) + h) * HDIM + t2 * 16 + ln] = f2b(acc[mt][t2][r] * inv);
    }
  }
}

// ---------------- fused mega-kernel: prep -> gemm0 -> attn -> gemm1 ----------------
__global__ __launch_bounds__(256, 3) void mega_kernel(
    const float* __restrict__ x, const float* __restrict__ Wq,
    const float* __restrict__ Wk, const float* __restrict__ Wv,
    const float* __restrict__ Wo, const float* __restrict__ bo,
    ushort* __restrict__ xb, ushort* __restrict__ Wtqkv, ushort* __restrict__ Wto,
    ushort* __restrict__ Qb, ushort* __restrict__ Kb, ushort* __restrict__ Vtb,
    float* __restrict__ out, unsigned* __restrict__ bar) {
  __shared__ LdsU lds;
  const int tid = threadIdx.x;
  const int blk = (int)blockIdx.x;
  const float SCALE_Q = 1.4426950408889634f / 8.0f;  // log2(e)/sqrt(D)

  // ---- phase P: cast x (blocks 0..511) + transpose/cast weights ----
  if (blk < 512) {
    size_t base0 = (size_t)blk * 16384 + tid * 4;
#pragma unroll
    for (int i = 0; i < 16; ++i) {
      float4 v = *(const float4*)(x + base0 + i * 1024);
      ushort4 o;
      o.x = f2b(v.x); o.y = f2b(v.y); o.z = f2b(v.z); o.w = f2b(v.w);
      *(ushort4*)(xb + base0 + i * 1024) = o;
    }
  }
  for (int t = blk; t < 4096; t += NBLK) {
    const int z = t >> 10, rem = t & 1023;
    const int k0 = (rem & 31) * 32, n0 = (rem >> 5) * 32;
    const float* W = z == 0 ? Wq : (z == 1 ? Wk : (z == 2 ? Wv : Wo));
    ushort* Wt = z == 0 ? Wtqkv : (z == 1 ? Wtqkv + 1048576 : (z == 2 ? Wtqkv + 2097152 : Wto));
    const float scale = z == 0 ? SCALE_Q : 1.0f;
    const int c = tid & 31, r0 = tid >> 5;
    __syncthreads();
#pragma unroll
    for (int i = 0; i < 4; ++i) {
      int r = r0 + i * 8;
      lds.wt[r][c] = W[(size_t)(k0 + r) * EMB + n0 + c];
    }
    __syncthreads();
#pragma unroll
    for (int i = 0; i < 4; ++i) {
      int r = r0 + i * 8;
      Wt[(size_t)(n0 + r) * EMB + k0 + c] = f2b(lds.wt[c][r] * scale);
    }
  }
  gridbar(bar);

  // ---- phase G0: QKV projection, 1536 tiles, 2 per block ----
  {
    int idx = blk;
    gemm_tile<0>(idx & 63, idx >> 6, xb, Wtqkv, EMB, 3072, Qb, Kb, Vtb, nullptr, nullptr, lds);
    idx = blk + NBLK;
    gemm_tile<0>(idx & 63, idx >> 6, xb, Wtqkv, EMB, 3072, Qb, Kb, Vtb, nullptr, nullptr, lds);
  }
  gridbar(bar);

  // ---- phase A: attention, 1024 jobs, LPT-balanced ----
  {
    ushort* Yb = xb;  // xb dead after G0
    if (blk < 512) {
      attn_job(blk & 63, 15 - (blk >> 6), Qb, Kb, Vtb, Yb, lds);   // 32..18 tiles
    } else {
      const int b2 = blk - 512, s = b2 >> 6;
      attn_job(b2 & 63, 7 - s, Qb, Kb, Vtb, Yb, lds);              // 16..10 tiles
      attn_job(b2 & 63, s, Qb, Kb, Vtb, Yb, lds);                  // 2..8 tiles
    }
  }
  gridbar(bar);

  // ---- phase G1: output projection, 512 tiles, blocks 0..511 ----
  if (blk < 512)
    gemm_tile<1>(blk & 63, blk >> 6, xb /*=Yb*/, Wto, EMB, EMB,
                 nullptr, nullptr, nullptr, out, bo, lds);
}

extern "C" void kernel_launch(void* const* d_in, const int* in_sizes, int n_in,
                              void* d_out, int out_size, void* d_ws, size_t ws_size,
                              hipStream_t stream) {
  const float* x  = (const float*)d_in[0];
  const float* Wq = (const float*)d_in[1];
  const float* Wk = (const float*)d_in[2];
  const float* Wv = (const float*)d_in[3];
  const float* Wo = (const float*)d_in[4];
  const float* bo = (const float*)d_in[5];
  float* out = (float*)d_out;

  const size_t XE = (size_t)8192 * EMB;  // 8388608
  ushort* ws    = (ushort*)d_ws;
  ushort* xb    = ws;
  ushort* Wtqkv = xb + XE;
  ushort* Wto   = Wtqkv + 3 * 1048576;
  ushort* Qb    = Wto + 1048576;
  ushort* Kb    = Qb + XE;
  ushort* Vtb   = Kb + XE;
  unsigned* bar = (unsigned*)(Vtb + XE);

  hipMemsetAsync(bar, 0, 16, stream);  // ws is re-poisoned 0xAA before every call
  mega_kernel<<<NBLK, 256, 0, stream>>>(x, Wq, Wk, Wv, Wo, bo,
                                        xb, Wtqkv, Wto, Qb, Kb, Vtb, out, bar);
}